// Round 5
// baseline (515.164 us; speedup 1.0000x reference)
//
#include <hip/hip_runtime.h>
#include <stdint.h>

#define NV 16384
#define DH 64
#define BTS (NV + 64)      // bf16 Bt row stride (elements)
#define BTQS (NV + 64)     // fp8 Btq row stride (bytes)
#define BK 256             // K-chunk (columns per LDS stage)
#define LDST 264           // bf16 LDS row stride (ushorts)
#define LDST8 272          // fp8 LDS row stride (bytes)
#define NCH 32             // chunks per half: 8192/256
#define SCUP 16384.0f      // adj scale into fp8 range (exact pow2)
#define SCDN 6.103515625e-05f

typedef __attribute__((ext_vector_type(4))) float f32x4;
typedef __attribute__((ext_vector_type(8))) short s16x8;

static __device__ __forceinline__ unsigned short f2bf(float f) {
  union { float f; unsigned u; } x; x.f = f;
  unsigned r = x.u + 0x7fffu + ((x.u >> 16) & 1u);
  return (unsigned short)(r >> 16);
}

static __device__ __forceinline__ s16x8 cvt8(f32x4 a, f32x4 b) {
  s16x8 r;
  r[0] = (short)f2bf(a[0]); r[1] = (short)f2bf(a[1]);
  r[2] = (short)f2bf(a[2]); r[3] = (short)f2bf(a[3]);
  r[4] = (short)f2bf(b[0]); r[5] = (short)f2bf(b[1]);
  r[6] = (short)f2bf(b[2]); r[7] = (short)f2bf(b[3]);
  return r;
}

// prep: Z[i][c] = (h@W1)[i][c] fp32 ; Bt[c][i] = bf16((h@L1)[i][c])
__global__ __launch_bounds__(256) void k_prep(
    const float* __restrict__ h, const float* __restrict__ W1,
    const float* __restrict__ L1, float* __restrict__ Z,
    unsigned short* __restrict__ Bt) {
  __shared__ float Ws[4096], Ls[4096], hs[16 * 64];
  int tid = threadIdx.x;
  for (int i = tid; i < 4096; i += 256) { Ws[i] = W1[i]; Ls[i] = L1[i]; }
  int r = tid >> 6, c = tid & 63;
  int i0 = blockIdx.x << 4;
  #pragma unroll
  for (int m = 0; m < 4; ++m)
    hs[(r + 4 * m) * 64 + c] = h[(size_t)(i0 + r + 4 * m) * 64 + c];
  __syncthreads();
  float a1[4] = {0.f, 0.f, 0.f, 0.f};
  float a2[4] = {0.f, 0.f, 0.f, 0.f};
  #pragma unroll 8
  for (int k = 0; k < 64; ++k) {
    float wv = Ws[k * 64 + c];
    float lv = Ls[k * 64 + c];
    #pragma unroll
    for (int m = 0; m < 4; ++m) {
      float hv = hs[(r + 4 * m) * 64 + k];
      a1[m] += hv * wv;
      a2[m] += hv * lv;
    }
  }
  #pragma unroll
  for (int m = 0; m < 4; ++m) {
    int i = i0 + r + 4 * m;
    Z[(size_t)i * 64 + c] = a1[m];
    Bt[(size_t)c * BTS + i] = f2bf(a2[m]);
  }
}

// layer-1 big: P[y] = adj @ B1 (bf16 MFMA); also emits adj8 = fp8(adj*2^14).
__global__ __launch_bounds__(256, 2) void k_adj(
    const float* __restrict__ adj, const unsigned short* __restrict__ Bt,
    float* __restrict__ P, unsigned char* __restrict__ adj8) {
  __shared__ __align__(16) unsigned short Blds[2 * 64 * LDST];
  const int tid = threadIdx.x;
  const int lane = tid & 63;
  const int w = tid >> 6;
  const int l15 = lane & 15;
  const int kgrp = lane >> 4;
  const int xb = blockIdx.x;
  const int yb = blockIdx.y;
  const int row = (xb << 6) + (w << 4) + l15;
  const int kbase = yb << 13;

  const int srow = tid >> 4;
  const int sc16 = tid & 15;
  const unsigned short* sbase = Bt + (size_t)srow * BTS + kbase + sc16 * 8;
  unsigned short* lbase = Blds + srow * LDST + sc16 * 8;

  const float* ap = adj + (size_t)row * NV + kbase + kgrp * 8;
  unsigned char* a8 = adj8 + (size_t)row * NV + kbase + kgrp * 8;
  const int bofs0 = (l15 +  0) * LDST + kgrp * 8;
  const int bofs1 = (l15 + 16) * LDST + kgrp * 8;
  const int bofs2 = (l15 + 32) * LDST + kgrp * 8;
  const int bofs3 = (l15 + 48) * LDST + kgrp * 8;

  f32x4 sr0, sr1, sr2, sr3, sr4, sr5, sr6, sr7;
#define STAGE_LOAD(KC)                                                   \
  { const unsigned short* s_ = sbase + (KC);                             \
    sr0 = *(const f32x4*)(s_);                                           \
    sr1 = *(const f32x4*)(s_ + 128);                                     \
    sr2 = *(const f32x4*)(s_ + (size_t)16 * BTS);                        \
    sr3 = *(const f32x4*)(s_ + (size_t)16 * BTS + 128);                  \
    sr4 = *(const f32x4*)(s_ + (size_t)32 * BTS);                        \
    sr5 = *(const f32x4*)(s_ + (size_t)32 * BTS + 128);                  \
    sr6 = *(const f32x4*)(s_ + (size_t)48 * BTS);                        \
    sr7 = *(const f32x4*)(s_ + (size_t)48 * BTS + 128); }
#define STAGE_WRITE(BUF)                                                 \
  { unsigned short* d_ = lbase + (BUF) * (64 * LDST);                    \
    *(f32x4*)(d_) = sr0;                                                 \
    *(f32x4*)(d_ + 128) = sr1;                                           \
    *(f32x4*)(d_ + 16 * LDST) = sr2;                                     \
    *(f32x4*)(d_ + 16 * LDST + 128) = sr3;                               \
    *(f32x4*)(d_ + 32 * LDST) = sr4;                                     \
    *(f32x4*)(d_ + 32 * LDST + 128) = sr5;                               \
    *(f32x4*)(d_ + 48 * LDST) = sr6;                                     \
    *(f32x4*)(d_ + 48 * LDST + 128) = sr7; }

  f32x4 aj0a, aj0b, aj1a, aj1b, aj2a, aj2b, aj3a, aj3b;

  STAGE_LOAD(0);
  aj0a = *(const f32x4*)(ap +   0); aj0b = *(const f32x4*)(ap +   4);
  aj1a = *(const f32x4*)(ap +  32); aj1b = *(const f32x4*)(ap +  36);
  aj2a = *(const f32x4*)(ap +  64); aj2b = *(const f32x4*)(ap +  68);
  aj3a = *(const f32x4*)(ap +  96); aj3b = *(const f32x4*)(ap + 100);
  STAGE_WRITE(0);
  __syncthreads();

  f32x4 acc0 = {0.f, 0.f, 0.f, 0.f};
  f32x4 acc1 = {0.f, 0.f, 0.f, 0.f};
  f32x4 acc2 = {0.f, 0.f, 0.f, 0.f};
  f32x4 acc3 = {0.f, 0.f, 0.f, 0.f};

#define ITER(II, AJA, AJB)                                               \
  {                                                                      \
    s16x8 af = cvt8(AJA, AJB);                                           \
    unsigned pk0 = __builtin_amdgcn_cvt_pk_fp8_f32(AJA[0] * SCUP, AJA[1] * SCUP, 0, false); \
    pk0 = __builtin_amdgcn_cvt_pk_fp8_f32(AJA[2] * SCUP, AJA[3] * SCUP, pk0, true);         \
    unsigned pk1 = __builtin_amdgcn_cvt_pk_fp8_f32(AJB[0] * SCUP, AJB[1] * SCUP, 0, false); \
    pk1 = __builtin_amdgcn_cvt_pk_fp8_f32(AJB[2] * SCUP, AJB[3] * SCUP, pk1, true);         \
    *(unsigned long long*)(a8 + (size_t)(((t << 3) + (II)) * 32)) =      \
        (unsigned long long)pk0 | ((unsigned long long)pk1 << 32);       \
    int ci = ((t << 3) + (II) + 4) & 255;                                \
    AJA = *(const f32x4*)(ap + (size_t)ci * 32);                         \
    AJB = *(const f32x4*)(ap + (size_t)ci * 32 + 4);                     \
    s16x8 cb0 = *(const s16x8*)(bb + bofs0 + (II) * 32);                 \
    s16x8 cb1 = *(const s16x8*)(bb + bofs1 + (II) * 32);                 \
    s16x8 cb2 = *(const s16x8*)(bb + bofs2 + (II) * 32);                 \
    s16x8 cb3 = *(const s16x8*)(bb + bofs3 + (II) * 32);                 \
    acc0 = __builtin_amdgcn_mfma_f32_16x16x32_bf16(af, cb0, acc0, 0, 0, 0); \
    acc1 = __builtin_amdgcn_mfma_f32_16x16x32_bf16(af, cb1, acc1, 0, 0, 0); \
    acc2 = __builtin_amdgcn_mfma_f32_16x16x32_bf16(af, cb2, acc2, 0, 0, 0); \
    acc3 = __builtin_amdgcn_mfma_f32_16x16x32_bf16(af, cb3, acc3, 0, 0, 0); \
  }

  for (int t = 0; t < NCH; ++t) {
    const unsigned short* bb = Blds + (t & 1) * (64 * LDST);
    if (t + 1 < NCH) STAGE_LOAD((t + 1) * BK);
    ITER(0, aj0a, aj0b)
    ITER(1, aj1a, aj1b)
    ITER(2, aj2a, aj2b)
    ITER(3, aj3a, aj3b)
    ITER(4, aj0a, aj0b)
    ITER(5, aj1a, aj1b)
    ITER(6, aj2a, aj2b)
    ITER(7, aj3a, aj3b)
    if (t + 1 < NCH) STAGE_WRITE((t + 1) & 1);
    __syncthreads();
  }

  int zr = (xb << 6) + (w << 4) + (kgrp << 2);
  float* pp = P + (size_t)yb * NV * 64 + (size_t)zr * 64 + l15;
  #pragma unroll
  for (int r = 0; r < 4; ++r) {
    pp[(size_t)r * 64 +  0] = acc0[r];
    pp[(size_t)r * 64 + 16] = acc1[r];
    pp[(size_t)r * 64 + 32] = acc2[r];
    pp[(size_t)r * 64 + 48] = acc3[r];
  }
#undef STAGE_LOAD
#undef STAGE_WRITE
#undef ITER
}

// layer-2 big: P[y] = (adj8 * 2^-14) @ B2  (fp8_fp8 MFMA), Btq fp8 LDS-staged.
__global__ __launch_bounds__(256, 2) void k_adj8(
    const unsigned char* __restrict__ adj8, const unsigned char* __restrict__ Btq,
    float* __restrict__ P) {
  __shared__ __align__(16) unsigned char Blds[2 * 64 * LDST8];
  const int tid = threadIdx.x;
  const int lane = tid & 63;
  const int w = tid >> 6;
  const int l15 = lane & 15;
  const int kgrp = lane >> 4;
  const int xb = blockIdx.x;
  const int yb = blockIdx.y;
  const int row = (xb << 6) + (w << 4) + l15;
  const int kbase = yb << 13;

  const int srow = tid >> 4;
  const int sc16 = tid & 15;
  const unsigned char* sbase = Btq + (size_t)srow * BTQS + kbase + sc16 * 16;
  unsigned char* lbase = Blds + srow * LDST8 + sc16 * 16;

  const unsigned char* ap8 = adj8 + (size_t)row * NV + kbase + kgrp * 8;
  const int bofs0 = (l15 +  0) * LDST8 + kgrp * 8;
  const int bofs1 = (l15 + 16) * LDST8 + kgrp * 8;
  const int bofs2 = (l15 + 32) * LDST8 + kgrp * 8;
  const int bofs3 = (l15 + 48) * LDST8 + kgrp * 8;

  f32x4 sr0, sr1, sr2, sr3;
#define STAGE_LOAD8(KC)                                                  \
  { const unsigned char* s_ = sbase + (KC);                              \
    sr0 = *(const f32x4*)(s_);                                           \
    sr1 = *(const f32x4*)(s_ + (size_t)16 * BTQS);                       \
    sr2 = *(const f32x4*)(s_ + (size_t)32 * BTQS);                       \
    sr3 = *(const f32x4*)(s_ + (size_t)48 * BTQS); }
#define STAGE_WRITE8(BUF)                                                \
  { unsigned char* d_ = lbase + (BUF) * (64 * LDST8);                    \
    *(f32x4*)(d_) = sr0;                                                 \
    *(f32x4*)(d_ + 16 * LDST8) = sr1;                                    \
    *(f32x4*)(d_ + 32 * LDST8) = sr2;                                    \
    *(f32x4*)(d_ + 48 * LDST8) = sr3; }

  unsigned long long aj0, aj1, aj2, aj3;

  STAGE_LOAD8(0);
  aj0 = *(const unsigned long long*)(ap8 +  0);
  aj1 = *(const unsigned long long*)(ap8 + 32);
  aj2 = *(const unsigned long long*)(ap8 + 64);
  aj3 = *(const unsigned long long*)(ap8 + 96);
  STAGE_WRITE8(0);
  __syncthreads();

  f32x4 acc0 = {0.f, 0.f, 0.f, 0.f};
  f32x4 acc1 = {0.f, 0.f, 0.f, 0.f};
  f32x4 acc2 = {0.f, 0.f, 0.f, 0.f};
  f32x4 acc3 = {0.f, 0.f, 0.f, 0.f};

#define ITER8(II, AJ)                                                    \
  {                                                                      \
    long long a_ = (long long)AJ;                                        \
    int ci = ((t << 3) + (II) + 4) & 255;                                \
    AJ = *(const unsigned long long*)(ap8 + (size_t)ci * 32);            \
    long long b0 = *(const long long*)(bb + bofs0 + (II) * 32);          \
    long long b1 = *(const long long*)(bb + bofs1 + (II) * 32);          \
    long long b2 = *(const long long*)(bb + bofs2 + (II) * 32);          \
    long long b3 = *(const long long*)(bb + bofs3 + (II) * 32);          \
    acc0 = __builtin_amdgcn_mfma_f32_16x16x32_fp8_fp8(a_, b0, acc0, 0, 0, 0); \
    acc1 = __builtin_amdgcn_mfma_f32_16x16x32_fp8_fp8(a_, b1, acc1, 0, 0, 0); \
    acc2 = __builtin_amdgcn_mfma_f32_16x16x32_fp8_fp8(a_, b2, acc2, 0, 0, 0); \
    acc3 = __builtin_amdgcn_mfma_f32_16x16x32_fp8_fp8(a_, b3, acc3, 0, 0, 0); \
  }

  for (int t = 0; t < NCH; ++t) {
    const unsigned char* bb = Blds + (t & 1) * (64 * LDST8);
    if (t + 1 < NCH) STAGE_LOAD8((t + 1) * BK);
    ITER8(0, aj0)
    ITER8(1, aj1)
    ITER8(2, aj2)
    ITER8(3, aj3)
    ITER8(4, aj0)
    ITER8(5, aj1)
    ITER8(6, aj2)
    ITER8(7, aj3)
    if (t + 1 < NCH) STAGE_WRITE8((t + 1) & 1);
    __syncthreads();
  }

  int zr = (xb << 6) + (w << 4) + (kgrp << 2);
  float* pp = P + (size_t)yb * NV * 64 + (size_t)zr * 64 + l15;
  #pragma unroll
  for (int r = 0; r < 4; ++r) {
    pp[(size_t)r * 64 +  0] = acc0[r] * SCDN;
    pp[(size_t)r * 64 + 16] = acc1[r] * SCDN;
    pp[(size_t)r * 64 + 32] = acc2[r] * SCDN;
    pp[(size_t)r * 64 + 48] = acc3[r] * SCDN;
  }
#undef STAGE_LOAD8
#undef STAGE_WRITE8
#undef ITER8
}

// mid: x = relu((Z+P0+P1)*rw1[reg]+rb1[reg]); Z = x@W2; Btq = fp8((x@L2)^T)
__global__ __launch_bounds__(256) void k_mid(
    float* __restrict__ Z, const float* __restrict__ P,
    const int* __restrict__ reg,
    const float* __restrict__ rw1, const float* __restrict__ rb1,
    const float* __restrict__ W2, const float* __restrict__ L2,
    unsigned char* __restrict__ Btq) {
  __shared__ float Ws[4096], Ls[4096], xs[16 * 64];
  int tid = threadIdx.x;
  for (int i = tid; i < 4096; i += 256) { Ws[i] = W2[i]; Ls[i] = L2[i]; }
  int r = tid >> 6, c = tid & 63;
  int i0 = blockIdx.x << 4;
  #pragma unroll
  for (int m = 0; m < 4; ++m) {
    int i = i0 + r + 4 * m;
    int ri = reg[i];
    size_t o = (size_t)i * 64 + c;
    float z = Z[o] + P[o] + P[(size_t)NV * 64 + o];
    float x = z * rw1[ri * 64 + c] + rb1[ri * 64 + c];
    xs[(r + 4 * m) * 64 + c] = fmaxf(x, 0.f);
  }
  __syncthreads();
  float a1[4] = {0.f, 0.f, 0.f, 0.f};
  float a2[4] = {0.f, 0.f, 0.f, 0.f};
  #pragma unroll 8
  for (int k = 0; k < 64; ++k) {
    float wv = Ws[k * 64 + c];
    float lv = Ls[k * 64 + c];
    #pragma unroll
    for (int m = 0; m < 4; ++m) {
      float xv = xs[(r + 4 * m) * 64 + k];
      a1[m] += xv * wv;
      a2[m] += xv * lv;
    }
  }
  #pragma unroll
  for (int m = 0; m < 4; ++m) {
    int i = i0 + r + 4 * m;
    Z[(size_t)i * 64 + c] = a1[m];
    unsigned q = __builtin_amdgcn_cvt_pk_fp8_f32(a2[m], 0.0f, 0, false);
    Btq[(size_t)c * BTQS + i] = (unsigned char)(q & 0xff);
  }
}

// out: x2 = relu((Z+P0+P1)*rw2[reg]+rb2[reg]); out = x2 @ Wout^T + bout
__global__ __launch_bounds__(256) void k_out(
    const float* __restrict__ Z, const float* __restrict__ P,
    const int* __restrict__ reg,
    const float* __restrict__ rw2, const float* __restrict__ rb2,
    const float* __restrict__ Wout, const float* __restrict__ bout,
    float* __restrict__ out) {
  __shared__ float xs[16 * 64];
  int tid = threadIdx.x;
  int r = tid >> 6, c = tid & 63;
  int i0 = blockIdx.x << 4;
  #pragma unroll
  for (int m = 0; m < 4; ++m) {
    int i = i0 + r + 4 * m;
    int ri = reg[i];
    size_t o = (size_t)i * 64 + c;
    float z = Z[o] + P[o] + P[(size_t)NV * 64 + o];
    float x = z * rw2[ri * 64 + c] + rb2[ri * 64 + c];
    xs[(r + 4 * m) * 64 + c] = fmaxf(x, 0.f);
  }
  __syncthreads();
  if (c < 8) {
    #pragma unroll
    for (int m = 0; m < 4; ++m) {
      int i = i0 + r + 4 * m;
      float a = bout[c];
      #pragma unroll 8
      for (int k = 0; k < 64; ++k) a += xs[(r + 4 * m) * 64 + k] * Wout[c * 64 + k];
      out[(size_t)i * 8 + c] = a;
    }
  }
}

extern "C" void kernel_launch(void* const* d_in, const int* in_sizes, int n_in,
                              void* d_out, int out_size, void* d_ws, size_t ws_size,
                              hipStream_t stream) {
  const float* h    = (const float*)d_in[0];
  const float* adj  = (const float*)d_in[1];
  const int*   reg  = (const int*)d_in[2];
  const float* W1   = (const float*)d_in[3];
  const float* L1   = (const float*)d_in[4];
  const float* rw1  = (const float*)d_in[5];
  const float* rb1  = (const float*)d_in[6];
  const float* W2   = (const float*)d_in[7];
  const float* L2   = (const float*)d_in[8];
  const float* rw2  = (const float*)d_in[9];
  const float* rb2  = (const float*)d_in[10];
  const float* Wout = (const float*)d_in[11];
  const float* bout = (const float*)d_in[12];
  float* out = (float*)d_out;

  char* ws = (char*)d_ws;
  float* Z            = (float*)(ws);                          // 4 MB @ 0
  unsigned short* Bt  = (unsigned short*)(ws + ((size_t)4  << 20));   // ~2.1 MB
  float* P            = (float*)(ws + ((size_t)8  << 20));    // 8 MB
  unsigned char* Btq  = (unsigned char*)(ws + ((size_t)16 << 20));    // ~1.05 MB
  unsigned char* adj8 = (unsigned char*)(ws + ((size_t)20 << 20));    // 256 MB

  k_prep<<<NV / 16, 256, 0, stream>>>(h, W1, L1, Z, Bt);
  k_adj<<<dim3(NV / 64, 2), 256, 0, stream>>>(adj, Bt, P, adj8);
  k_mid<<<NV / 16, 256, 0, stream>>>(Z, P, reg, rw1, rb1, W2, L2, Btq);
  k_adj8<<<dim3(NV / 64, 2), 256, 0, stream>>>(adj8, Btq, P);
  k_out<<<NV / 16, 256, 0, stream>>>(Z, P, reg, rw2, rb2, Wout, bout, out);
}

// Round 6
// 405.560 us; speedup vs baseline: 1.2703x; 1.2703x over previous
//
#include <hip/hip_runtime.h>
#include <stdint.h>

#define NV 16384
#define DH 64
#define BTS (NV + 64)      // bf16 Bt row stride (elements)
#define BTQS (NV + 64)     // fp8 Btq row stride (bytes)
#define BK 256             // K-chunk (columns per LDS stage)
#define LDST 264           // bf16 LDS row stride (ushorts)
#define LDST8 272          // fp8 LDS row stride (bytes)
#define NCH 32             // chunks per half: 8192/256
#define SCUP 16384.0f      // adj scale into fp8 range (exact pow2)
#define SCDN 6.103515625e-05f

typedef __attribute__((ext_vector_type(4))) float f32x4;
typedef __attribute__((ext_vector_type(8))) short s16x8;

static __device__ __forceinline__ unsigned short f2bf(float f) {
  union { float f; unsigned u; } x; x.f = f;
  unsigned r = x.u + 0x7fffu + ((x.u >> 16) & 1u);
  return (unsigned short)(r >> 16);
}

static __device__ __forceinline__ s16x8 cvt8(f32x4 a, f32x4 b) {
  s16x8 r;
  r[0] = (short)f2bf(a[0]); r[1] = (short)f2bf(a[1]);
  r[2] = (short)f2bf(a[2]); r[3] = (short)f2bf(a[3]);
  r[4] = (short)f2bf(b[0]); r[5] = (short)f2bf(b[1]);
  r[6] = (short)f2bf(b[2]); r[7] = (short)f2bf(b[3]);
  return r;
}

// prep: Z[i][c] = (h@W1)[i][c] fp32 ; Bt[c][i] = bf16((h@L1)[i][c])
__global__ __launch_bounds__(256) void k_prep(
    const float* __restrict__ h, const float* __restrict__ W1,
    const float* __restrict__ L1, float* __restrict__ Z,
    unsigned short* __restrict__ Bt) {
  __shared__ float Ws[4096], Ls[4096], hs[16 * 64];
  int tid = threadIdx.x;
  for (int i = tid; i < 4096; i += 256) { Ws[i] = W1[i]; Ls[i] = L1[i]; }
  int r = tid >> 6, c = tid & 63;
  int i0 = blockIdx.x << 4;
  #pragma unroll
  for (int m = 0; m < 4; ++m)
    hs[(r + 4 * m) * 64 + c] = h[(size_t)(i0 + r + 4 * m) * 64 + c];
  __syncthreads();
  float a1[4] = {0.f, 0.f, 0.f, 0.f};
  float a2[4] = {0.f, 0.f, 0.f, 0.f};
  #pragma unroll 8
  for (int k = 0; k < 64; ++k) {
    float wv = Ws[k * 64 + c];
    float lv = Ls[k * 64 + c];
    #pragma unroll
    for (int m = 0; m < 4; ++m) {
      float hv = hs[(r + 4 * m) * 64 + k];
      a1[m] += hv * wv;
      a2[m] += hv * lv;
    }
  }
  #pragma unroll
  for (int m = 0; m < 4; ++m) {
    int i = i0 + r + 4 * m;
    Z[(size_t)i * 64 + c] = a1[m];
    Bt[(size_t)c * BTS + i] = f2bf(a2[m]);
  }
}

// layer-1 big: P[y] = adj @ B1 (bf16 MFMA); emits adj8 in FRAGMENT-MAJOR layout:
// offset = (((xb*2+yb)*4+w)*256 + iter)*512 + lane*8  -> 512B contiguous per
// wave-ITER store (fixes R5's 16x32B scattered-write RMW penalty).
__global__ __launch_bounds__(256, 2) void k_adj(
    const float* __restrict__ adj, const unsigned short* __restrict__ Bt,
    float* __restrict__ P, unsigned char* __restrict__ adj8) {
  __shared__ __align__(16) unsigned short Blds[2 * 64 * LDST];
  const int tid = threadIdx.x;
  const int lane = tid & 63;
  const int w = tid >> 6;
  const int l15 = lane & 15;
  const int kgrp = lane >> 4;
  const int xb = blockIdx.x;
  const int yb = blockIdx.y;
  const int row = (xb << 6) + (w << 4) + l15;
  const int kbase = yb << 13;

  const int srow = tid >> 4;
  const int sc16 = tid & 15;
  const unsigned short* sbase = Bt + (size_t)srow * BTS + kbase + sc16 * 8;
  unsigned short* lbase = Blds + srow * LDST + sc16 * 8;

  const float* ap = adj + (size_t)row * NV + kbase + kgrp * 8;
  unsigned char* a8w = adj8 +
      ((((size_t)xb * 2 + yb) * 4 + w) * 256) * 512 + (size_t)lane * 8;
  const int bofs0 = (l15 +  0) * LDST + kgrp * 8;
  const int bofs1 = (l15 + 16) * LDST + kgrp * 8;
  const int bofs2 = (l15 + 32) * LDST + kgrp * 8;
  const int bofs3 = (l15 + 48) * LDST + kgrp * 8;

  f32x4 sr0, sr1, sr2, sr3, sr4, sr5, sr6, sr7;
#define STAGE_LOAD(KC)                                                   \
  { const unsigned short* s_ = sbase + (KC);                             \
    sr0 = *(const f32x4*)(s_);                                           \
    sr1 = *(const f32x4*)(s_ + 128);                                     \
    sr2 = *(const f32x4*)(s_ + (size_t)16 * BTS);                        \
    sr3 = *(const f32x4*)(s_ + (size_t)16 * BTS + 128);                  \
    sr4 = *(const f32x4*)(s_ + (size_t)32 * BTS);                        \
    sr5 = *(const f32x4*)(s_ + (size_t)32 * BTS + 128);                  \
    sr6 = *(const f32x4*)(s_ + (size_t)48 * BTS);                        \
    sr7 = *(const f32x4*)(s_ + (size_t)48 * BTS + 128); }
#define STAGE_WRITE(BUF)                                                 \
  { unsigned short* d_ = lbase + (BUF) * (64 * LDST);                    \
    *(f32x4*)(d_) = sr0;                                                 \
    *(f32x4*)(d_ + 128) = sr1;                                           \
    *(f32x4*)(d_ + 16 * LDST) = sr2;                                     \
    *(f32x4*)(d_ + 16 * LDST + 128) = sr3;                               \
    *(f32x4*)(d_ + 32 * LDST) = sr4;                                     \
    *(f32x4*)(d_ + 32 * LDST + 128) = sr5;                               \
    *(f32x4*)(d_ + 48 * LDST) = sr6;                                     \
    *(f32x4*)(d_ + 48 * LDST + 128) = sr7; }

  f32x4 aj0a, aj0b, aj1a, aj1b, aj2a, aj2b, aj3a, aj3b;

  STAGE_LOAD(0);
  aj0a = *(const f32x4*)(ap +   0); aj0b = *(const f32x4*)(ap +   4);
  aj1a = *(const f32x4*)(ap +  32); aj1b = *(const f32x4*)(ap +  36);
  aj2a = *(const f32x4*)(ap +  64); aj2b = *(const f32x4*)(ap +  68);
  aj3a = *(const f32x4*)(ap +  96); aj3b = *(const f32x4*)(ap + 100);
  STAGE_WRITE(0);
  __syncthreads();

  f32x4 acc0 = {0.f, 0.f, 0.f, 0.f};
  f32x4 acc1 = {0.f, 0.f, 0.f, 0.f};
  f32x4 acc2 = {0.f, 0.f, 0.f, 0.f};
  f32x4 acc3 = {0.f, 0.f, 0.f, 0.f};

#define ITER(II, AJA, AJB)                                               \
  {                                                                      \
    s16x8 af = cvt8(AJA, AJB);                                           \
    unsigned pk0 = __builtin_amdgcn_cvt_pk_fp8_f32(AJA[0] * SCUP, AJA[1] * SCUP, 0, false); \
    pk0 = __builtin_amdgcn_cvt_pk_fp8_f32(AJA[2] * SCUP, AJA[3] * SCUP, pk0, true);         \
    unsigned pk1 = __builtin_amdgcn_cvt_pk_fp8_f32(AJB[0] * SCUP, AJB[1] * SCUP, 0, false); \
    pk1 = __builtin_amdgcn_cvt_pk_fp8_f32(AJB[2] * SCUP, AJB[3] * SCUP, pk1, true);         \
    *(unsigned long long*)(a8w + (size_t)((t << 3) + (II)) * 512) =      \
        (unsigned long long)pk0 | ((unsigned long long)pk1 << 32);       \
    int ci = ((t << 3) + (II) + 4) & 255;                                \
    AJA = *(const f32x4*)(ap + (size_t)ci * 32);                         \
    AJB = *(const f32x4*)(ap + (size_t)ci * 32 + 4);                     \
    s16x8 cb0 = *(const s16x8*)(bb + bofs0 + (II) * 32);                 \
    s16x8 cb1 = *(const s16x8*)(bb + bofs1 + (II) * 32);                 \
    s16x8 cb2 = *(const s16x8*)(bb + bofs2 + (II) * 32);                 \
    s16x8 cb3 = *(const s16x8*)(bb + bofs3 + (II) * 32);                 \
    acc0 = __builtin_amdgcn_mfma_f32_16x16x32_bf16(af, cb0, acc0, 0, 0, 0); \
    acc1 = __builtin_amdgcn_mfma_f32_16x16x32_bf16(af, cb1, acc1, 0, 0, 0); \
    acc2 = __builtin_amdgcn_mfma_f32_16x16x32_bf16(af, cb2, acc2, 0, 0, 0); \
    acc3 = __builtin_amdgcn_mfma_f32_16x16x32_bf16(af, cb3, acc3, 0, 0, 0); \
  }

  for (int t = 0; t < NCH; ++t) {
    const unsigned short* bb = Blds + (t & 1) * (64 * LDST);
    if (t + 1 < NCH) STAGE_LOAD((t + 1) * BK);
    ITER(0, aj0a, aj0b)
    ITER(1, aj1a, aj1b)
    ITER(2, aj2a, aj2b)
    ITER(3, aj3a, aj3b)
    ITER(4, aj0a, aj0b)
    ITER(5, aj1a, aj1b)
    ITER(6, aj2a, aj2b)
    ITER(7, aj3a, aj3b)
    if (t + 1 < NCH) STAGE_WRITE((t + 1) & 1);
    __syncthreads();
  }

  int zr = (xb << 6) + (w << 4) + (kgrp << 2);
  float* pp = P + (size_t)yb * NV * 64 + (size_t)zr * 64 + l15;
  #pragma unroll
  for (int r = 0; r < 4; ++r) {
    pp[(size_t)r * 64 +  0] = acc0[r];
    pp[(size_t)r * 64 + 16] = acc1[r];
    pp[(size_t)r * 64 + 32] = acc2[r];
    pp[(size_t)r * 64 + 48] = acc3[r];
  }
#undef STAGE_LOAD
#undef STAGE_WRITE
#undef ITER
}

// layer-2 big: P[y] = (adj8 * 2^-14) @ B2 (fp8_fp8 MFMA). adj8 is fragment-major
// (512B contiguous per wave-ITER load); Btq fp8 LDS-staged.
__global__ __launch_bounds__(256, 2) void k_adj8(
    const unsigned char* __restrict__ adj8, const unsigned char* __restrict__ Btq,
    float* __restrict__ P) {
  __shared__ __align__(16) unsigned char Blds[2 * 64 * LDST8];
  const int tid = threadIdx.x;
  const int lane = tid & 63;
  const int w = tid >> 6;
  const int l15 = lane & 15;
  const int kgrp = lane >> 4;
  const int xb = blockIdx.x;
  const int yb = blockIdx.y;
  const int kbase = yb << 13;

  const int srow = tid >> 4;
  const int sc16 = tid & 15;
  const unsigned char* sbase = Btq + (size_t)srow * BTQS + kbase + sc16 * 16;
  unsigned char* lbase = Blds + srow * LDST8 + sc16 * 16;

  const unsigned char* ap8 = adj8 +
      ((((size_t)xb * 2 + yb) * 4 + w) * 256) * 512 + (size_t)lane * 8;
  const int bofs0 = (l15 +  0) * LDST8 + kgrp * 8;
  const int bofs1 = (l15 + 16) * LDST8 + kgrp * 8;
  const int bofs2 = (l15 + 32) * LDST8 + kgrp * 8;
  const int bofs3 = (l15 + 48) * LDST8 + kgrp * 8;

  f32x4 sr0, sr1, sr2, sr3;
#define STAGE_LOAD8(KC)                                                  \
  { const unsigned char* s_ = sbase + (KC);                              \
    sr0 = *(const f32x4*)(s_);                                           \
    sr1 = *(const f32x4*)(s_ + (size_t)16 * BTQS);                       \
    sr2 = *(const f32x4*)(s_ + (size_t)32 * BTQS);                       \
    sr3 = *(const f32x4*)(s_ + (size_t)48 * BTQS); }
#define STAGE_WRITE8(BUF)                                                \
  { unsigned char* d_ = lbase + (BUF) * (64 * LDST8);                    \
    *(f32x4*)(d_) = sr0;                                                 \
    *(f32x4*)(d_ + 16 * LDST8) = sr1;                                    \
    *(f32x4*)(d_ + 32 * LDST8) = sr2;                                    \
    *(f32x4*)(d_ + 48 * LDST8) = sr3; }

  unsigned long long aj0, aj1, aj2, aj3;

  STAGE_LOAD8(0);
  aj0 = *(const unsigned long long*)(ap8 +    0);
  aj1 = *(const unsigned long long*)(ap8 +  512);
  aj2 = *(const unsigned long long*)(ap8 + 1024);
  aj3 = *(const unsigned long long*)(ap8 + 1536);
  STAGE_WRITE8(0);
  __syncthreads();

  f32x4 acc0 = {0.f, 0.f, 0.f, 0.f};
  f32x4 acc1 = {0.f, 0.f, 0.f, 0.f};
  f32x4 acc2 = {0.f, 0.f, 0.f, 0.f};
  f32x4 acc3 = {0.f, 0.f, 0.f, 0.f};

#define ITER8(II, AJ)                                                    \
  {                                                                      \
    long long a_ = (long long)AJ;                                        \
    int ci = ((t << 3) + (II) + 4) & 255;                                \
    AJ = *(const unsigned long long*)(ap8 + (size_t)ci * 512);           \
    long long b0 = *(const long long*)(bb + bofs0 + (II) * 32);          \
    long long b1 = *(const long long*)(bb + bofs1 + (II) * 32);          \
    long long b2 = *(const long long*)(bb + bofs2 + (II) * 32);          \
    long long b3 = *(const long long*)(bb + bofs3 + (II) * 32);          \
    acc0 = __builtin_amdgcn_mfma_f32_16x16x32_fp8_fp8(a_, b0, acc0, 0, 0, 0); \
    acc1 = __builtin_amdgcn_mfma_f32_16x16x32_fp8_fp8(a_, b1, acc1, 0, 0, 0); \
    acc2 = __builtin_amdgcn_mfma_f32_16x16x32_fp8_fp8(a_, b2, acc2, 0, 0, 0); \
    acc3 = __builtin_amdgcn_mfma_f32_16x16x32_fp8_fp8(a_, b3, acc3, 0, 0, 0); \
  }

  for (int t = 0; t < NCH; ++t) {
    const unsigned char* bb = Blds + (t & 1) * (64 * LDST8);
    if (t + 1 < NCH) STAGE_LOAD8((t + 1) * BK);
    ITER8(0, aj0)
    ITER8(1, aj1)
    ITER8(2, aj2)
    ITER8(3, aj3)
    ITER8(4, aj0)
    ITER8(5, aj1)
    ITER8(6, aj2)
    ITER8(7, aj3)
    if (t + 1 < NCH) STAGE_WRITE8((t + 1) & 1);
    __syncthreads();
  }

  int zr = (xb << 6) + (w << 4) + (kgrp << 2);
  float* pp = P + (size_t)yb * NV * 64 + (size_t)zr * 64 + l15;
  #pragma unroll
  for (int r = 0; r < 4; ++r) {
    pp[(size_t)r * 64 +  0] = acc0[r] * SCDN;
    pp[(size_t)r * 64 + 16] = acc1[r] * SCDN;
    pp[(size_t)r * 64 + 32] = acc2[r] * SCDN;
    pp[(size_t)r * 64 + 48] = acc3[r] * SCDN;
  }
#undef STAGE_LOAD8
#undef STAGE_WRITE8
#undef ITER8
}

// mid: x = relu((Z+P0+P1)*rw1[reg]+rb1[reg]); Z = x@W2; Btq = fp8((x@L2)^T)
__global__ __launch_bounds__(256) void k_mid(
    float* __restrict__ Z, const float* __restrict__ P,
    const int* __restrict__ reg,
    const float* __restrict__ rw1, const float* __restrict__ rb1,
    const float* __restrict__ W2, const float* __restrict__ L2,
    unsigned char* __restrict__ Btq) {
  __shared__ float Ws[4096], Ls[4096], xs[16 * 64];
  int tid = threadIdx.x;
  for (int i = tid; i < 4096; i += 256) { Ws[i] = W2[i]; Ls[i] = L2[i]; }
  int r = tid >> 6, c = tid & 63;
  int i0 = blockIdx.x << 4;
  #pragma unroll
  for (int m = 0; m < 4; ++m) {
    int i = i0 + r + 4 * m;
    int ri = reg[i];
    size_t o = (size_t)i * 64 + c;
    float z = Z[o] + P[o] + P[(size_t)NV * 64 + o];
    float x = z * rw1[ri * 64 + c] + rb1[ri * 64 + c];
    xs[(r + 4 * m) * 64 + c] = fmaxf(x, 0.f);
  }
  __syncthreads();
  float a1[4] = {0.f, 0.f, 0.f, 0.f};
  float a2[4] = {0.f, 0.f, 0.f, 0.f};
  #pragma unroll 8
  for (int k = 0; k < 64; ++k) {
    float wv = Ws[k * 64 + c];
    float lv = Ls[k * 64 + c];
    #pragma unroll
    for (int m = 0; m < 4; ++m) {
      float xv = xs[(r + 4 * m) * 64 + k];
      a1[m] += xv * wv;
      a2[m] += xv * lv;
    }
  }
  #pragma unroll
  for (int m = 0; m < 4; ++m) {
    int i = i0 + r + 4 * m;
    Z[(size_t)i * 64 + c] = a1[m];
    unsigned q = __builtin_amdgcn_cvt_pk_fp8_f32(a2[m], 0.0f, 0, false);
    Btq[(size_t)c * BTQS + i] = (unsigned char)(q & 0xff);
  }
}

// out: x2 = relu((Z+P0+P1)*rw2[reg]+rb2[reg]); out = x2 @ Wout^T + bout
__global__ __launch_bounds__(256) void k_out(
    const float* __restrict__ Z, const float* __restrict__ P,
    const int* __restrict__ reg,
    const float* __restrict__ rw2, const float* __restrict__ rb2,
    const float* __restrict__ Wout, const float* __restrict__ bout,
    float* __restrict__ out) {
  __shared__ float xs[16 * 64];
  int tid = threadIdx.x;
  int r = tid >> 6, c = tid & 63;
  int i0 = blockIdx.x << 4;
  #pragma unroll
  for (int m = 0; m < 4; ++m) {
    int i = i0 + r + 4 * m;
    int ri = reg[i];
    size_t o = (size_t)i * 64 + c;
    float z = Z[o] + P[o] + P[(size_t)NV * 64 + o];
    float x = z * rw2[ri * 64 + c] + rb2[ri * 64 + c];
    xs[(r + 4 * m) * 64 + c] = fmaxf(x, 0.f);
  }
  __syncthreads();
  if (c < 8) {
    #pragma unroll
    for (int m = 0; m < 4; ++m) {
      int i = i0 + r + 4 * m;
      float a = bout[c];
      #pragma unroll 8
      for (int k = 0; k < 64; ++k) a += xs[(r + 4 * m) * 64 + k] * Wout[c * 64 + k];
      out[(size_t)i * 8 + c] = a;
    }
  }
}

extern "C" void kernel_launch(void* const* d_in, const int* in_sizes, int n_in,
                              void* d_out, int out_size, void* d_ws, size_t ws_size,
                              hipStream_t stream) {
  const float* h    = (const float*)d_in[0];
  const float* adj  = (const float*)d_in[1];
  const int*   reg  = (const int*)d_in[2];
  const float* W1   = (const float*)d_in[3];
  const float* L1   = (const float*)d_in[4];
  const float* rw1  = (const float*)d_in[5];
  const float* rb1  = (const float*)d_in[6];
  const float* W2   = (const float*)d_in[7];
  const float* L2   = (const float*)d_in[8];
  const float* rw2  = (const float*)d_in[9];
  const float* rb2  = (const float*)d_in[10];
  const float* Wout = (const float*)d_in[11];
  const float* bout = (const float*)d_in[12];
  float* out = (float*)d_out;

  char* ws = (char*)d_ws;
  float* Z            = (float*)(ws);                                 // 4 MB @ 0
  unsigned short* Bt  = (unsigned short*)(ws + ((size_t)4  << 20));   // ~2.1 MB
  float* P            = (float*)(ws + ((size_t)8  << 20));            // 8 MB
  unsigned char* Btq  = (unsigned char*)(ws + ((size_t)16 << 20));    // ~1.05 MB
  unsigned char* adj8 = (unsigned char*)(ws + ((size_t)20 << 20));    // 256 MB

  k_prep<<<NV / 16, 256, 0, stream>>>(h, W1, L1, Z, Bt);
  k_adj<<<dim3(NV / 64, 2), 256, 0, stream>>>(adj, Bt, P, adj8);
  k_mid<<<NV / 16, 256, 0, stream>>>(Z, P, reg, rw1, rb1, W2, L2, Btq);
  k_adj8<<<dim3(NV / 64, 2), 256, 0, stream>>>(adj8, Btq, P);
  k_out<<<NV / 16, 256, 0, stream>>>(Z, P, reg, rw2, rb2, Wout, bout, out);
}

// Round 7
// 395.479 us; speedup vs baseline: 1.3026x; 1.0255x over previous
//
#include <hip/hip_runtime.h>
#include <stdint.h>

#define NV 16384
#define BTQS (NV + 64)     // fp8 B-transpose row stride (bytes)
#define BK 256             // K-chunk (columns per LDS stage)
#define LDST8 272          // fp8 LDS row stride (bytes)
#define NCH 16             // chunks per K-quarter: 4096/256
#define SCUP 16384.0f      // adj scale into fp8 range (exact pow2)
#define SCDN 6.103515625e-05f

typedef __attribute__((ext_vector_type(4))) float f32x4;

// prep: Z[i][c] = (h@W1)[i][c] fp32 ; Btq1[c][i] = fp8((h@L1)[i][c])
__global__ __launch_bounds__(256) void k_prep(
    const float* __restrict__ h, const float* __restrict__ W1,
    const float* __restrict__ L1, float* __restrict__ Z,
    unsigned char* __restrict__ Btq1) {
  __shared__ float Ws[4096], Ls[4096], hs[16 * 64];
  int tid = threadIdx.x;
  for (int i = tid; i < 4096; i += 256) { Ws[i] = W1[i]; Ls[i] = L1[i]; }
  int r = tid >> 6, c = tid & 63;
  int i0 = blockIdx.x << 4;
  #pragma unroll
  for (int m = 0; m < 4; ++m)
    hs[(r + 4 * m) * 64 + c] = h[(size_t)(i0 + r + 4 * m) * 64 + c];
  __syncthreads();
  float a1[4] = {0.f, 0.f, 0.f, 0.f};
  float a2[4] = {0.f, 0.f, 0.f, 0.f};
  #pragma unroll 8
  for (int k = 0; k < 64; ++k) {
    float wv = Ws[k * 64 + c];
    float lv = Ls[k * 64 + c];
    #pragma unroll
    for (int m = 0; m < 4; ++m) {
      float hv = hs[(r + 4 * m) * 64 + k];
      a1[m] += hv * wv;
      a2[m] += hv * lv;
    }
  }
  #pragma unroll
  for (int m = 0; m < 4; ++m) {
    int i = i0 + r + 4 * m;
    Z[(size_t)i * 64 + c] = a1[m];
    unsigned q = __builtin_amdgcn_cvt_pk_fp8_f32(a2[m], 0.0f, 0, false);
    Btq1[(size_t)c * BTQS + i] = (unsigned char)(q & 0xff);
  }
}

// layer-1 big: P[y] = adj @ B1, fp8_fp8 MFMA. Packs adj*2^14 to fp8 ONCE:
// same register feeds the MFMA A-operand and the fragment-major adj8 store
// (offset = (((xb*4+yb)*4+w)*128 + iter)*512 + lane*8 -> 512B/wave-iter).
__global__ __launch_bounds__(256, 4) void k_adj1(
    const float* __restrict__ adj, const unsigned char* __restrict__ Btq,
    float* __restrict__ P, unsigned char* __restrict__ adj8) {
  __shared__ __align__(16) unsigned char Blds[2 * 64 * LDST8];
  const int tid = threadIdx.x;
  const int lane = tid & 63;
  const int w = tid >> 6;
  const int l15 = lane & 15;
  const int kgrp = lane >> 4;
  const int xb = blockIdx.x;
  const int yb = blockIdx.y;
  const int row = (xb << 6) + (w << 4) + l15;
  const int kbase = yb << 12;                 // 4096 per quarter

  const int srow = tid >> 4;
  const int sc16 = tid & 15;
  const unsigned char* sbase = Btq + (size_t)srow * BTQS + kbase + sc16 * 16;
  unsigned char* lbase = Blds + srow * LDST8 + sc16 * 16;

  const float* ap = adj + (size_t)row * NV + kbase + kgrp * 8;
  unsigned char* a8w = adj8 +
      ((((size_t)xb * 4 + yb) * 4 + w) * 128) * 512 + (size_t)lane * 8;
  const int bofs0 = (l15 +  0) * LDST8 + kgrp * 8;
  const int bofs1 = (l15 + 16) * LDST8 + kgrp * 8;
  const int bofs2 = (l15 + 32) * LDST8 + kgrp * 8;
  const int bofs3 = (l15 + 48) * LDST8 + kgrp * 8;

  f32x4 sr0, sr1, sr2, sr3;
#define STAGE_LOAD8(KC)                                                  \
  { const unsigned char* s_ = sbase + (KC);                              \
    sr0 = *(const f32x4*)(s_);                                           \
    sr1 = *(const f32x4*)(s_ + (size_t)16 * BTQS);                       \
    sr2 = *(const f32x4*)(s_ + (size_t)32 * BTQS);                       \
    sr3 = *(const f32x4*)(s_ + (size_t)48 * BTQS); }
#define STAGE_WRITE8(BUF)                                                \
  { unsigned char* d_ = lbase + (BUF) * (64 * LDST8);                    \
    *(f32x4*)(d_) = sr0;                                                 \
    *(f32x4*)(d_ + 16 * LDST8) = sr1;                                    \
    *(f32x4*)(d_ + 32 * LDST8) = sr2;                                    \
    *(f32x4*)(d_ + 48 * LDST8) = sr3; }

  f32x4 aj0a, aj0b, aj1a, aj1b, aj2a, aj2b, aj3a, aj3b;

  STAGE_LOAD8(0);
  aj0a = *(const f32x4*)(ap +   0); aj0b = *(const f32x4*)(ap +   4);
  aj1a = *(const f32x4*)(ap +  32); aj1b = *(const f32x4*)(ap +  36);
  aj2a = *(const f32x4*)(ap +  64); aj2b = *(const f32x4*)(ap +  68);
  aj3a = *(const f32x4*)(ap +  96); aj3b = *(const f32x4*)(ap + 100);
  STAGE_WRITE8(0);
  __syncthreads();

  f32x4 acc0 = {0.f, 0.f, 0.f, 0.f};
  f32x4 acc1 = {0.f, 0.f, 0.f, 0.f};
  f32x4 acc2 = {0.f, 0.f, 0.f, 0.f};
  f32x4 acc3 = {0.f, 0.f, 0.f, 0.f};

#define ITER1(II, AJA, AJB)                                              \
  {                                                                      \
    unsigned pk0 = __builtin_amdgcn_cvt_pk_fp8_f32(AJA[0] * SCUP, AJA[1] * SCUP, 0, false); \
    pk0 = __builtin_amdgcn_cvt_pk_fp8_f32(AJA[2] * SCUP, AJA[3] * SCUP, pk0, true);         \
    unsigned pk1 = __builtin_amdgcn_cvt_pk_fp8_f32(AJB[0] * SCUP, AJB[1] * SCUP, 0, false); \
    pk1 = __builtin_amdgcn_cvt_pk_fp8_f32(AJB[2] * SCUP, AJB[3] * SCUP, pk1, true);         \
    unsigned long long av = (unsigned long long)pk0 | ((unsigned long long)pk1 << 32); \
    *(unsigned long long*)(a8w + (size_t)((t << 3) + (II)) * 512) = av;  \
    long long a_ = (long long)av;                                        \
    int ci = ((t << 3) + (II) + 4) & 127;                                \
    AJA = *(const f32x4*)(ap + (size_t)ci * 32);                         \
    AJB = *(const f32x4*)(ap + (size_t)ci * 32 + 4);                     \
    long long b0 = *(const long long*)(bb + bofs0 + (II) * 32);          \
    long long b1 = *(const long long*)(bb + bofs1 + (II) * 32);          \
    long long b2 = *(const long long*)(bb + bofs2 + (II) * 32);          \
    long long b3 = *(const long long*)(bb + bofs3 + (II) * 32);          \
    acc0 = __builtin_amdgcn_mfma_f32_16x16x32_fp8_fp8(a_, b0, acc0, 0, 0, 0); \
    acc1 = __builtin_amdgcn_mfma_f32_16x16x32_fp8_fp8(a_, b1, acc1, 0, 0, 0); \
    acc2 = __builtin_amdgcn_mfma_f32_16x16x32_fp8_fp8(a_, b2, acc2, 0, 0, 0); \
    acc3 = __builtin_amdgcn_mfma_f32_16x16x32_fp8_fp8(a_, b3, acc3, 0, 0, 0); \
  }

  for (int t = 0; t < NCH; ++t) {
    const unsigned char* bb = Blds + (t & 1) * (64 * LDST8);
    if (t + 1 < NCH) STAGE_LOAD8((t + 1) * BK);
    ITER1(0, aj0a, aj0b)
    ITER1(1, aj1a, aj1b)
    ITER1(2, aj2a, aj2b)
    ITER1(3, aj3a, aj3b)
    ITER1(4, aj0a, aj0b)
    ITER1(5, aj1a, aj1b)
    ITER1(6, aj2a, aj2b)
    ITER1(7, aj3a, aj3b)
    if (t + 1 < NCH) STAGE_WRITE8((t + 1) & 1);
    __syncthreads();
  }

  // D layout: col = lane&15 (+16*f), row = (lane>>4)*4 + reg  [m89-verified]
  int zr = (xb << 6) + (w << 4) + (kgrp << 2);
  float* pp = P + (size_t)yb * NV * 64 + (size_t)zr * 64 + l15;
  #pragma unroll
  for (int r = 0; r < 4; ++r) {
    pp[(size_t)r * 64 +  0] = acc0[r] * SCDN;
    pp[(size_t)r * 64 + 16] = acc1[r] * SCDN;
    pp[(size_t)r * 64 + 32] = acc2[r] * SCDN;
    pp[(size_t)r * 64 + 48] = acc3[r] * SCDN;
  }
#undef ITER1
}

// layer-2 big: P[y] = (adj8 * 2^-14) @ B2 (fp8_fp8). adj8 fragment-major.
__global__ __launch_bounds__(256, 4) void k_adj8(
    const unsigned char* __restrict__ adj8, const unsigned char* __restrict__ Btq,
    float* __restrict__ P) {
  __shared__ __align__(16) unsigned char Blds[2 * 64 * LDST8];
  const int tid = threadIdx.x;
  const int lane = tid & 63;
  const int w = tid >> 6;
  const int l15 = lane & 15;
  const int kgrp = lane >> 4;
  const int xb = blockIdx.x;
  const int yb = blockIdx.y;
  const int kbase = yb << 12;

  const int srow = tid >> 4;
  const int sc16 = tid & 15;
  const unsigned char* sbase = Btq + (size_t)srow * BTQS + kbase + sc16 * 16;
  unsigned char* lbase = Blds + srow * LDST8 + sc16 * 16;

  const unsigned char* ap8 = adj8 +
      ((((size_t)xb * 4 + yb) * 4 + w) * 128) * 512 + (size_t)lane * 8;
  const int bofs0 = (l15 +  0) * LDST8 + kgrp * 8;
  const int bofs1 = (l15 + 16) * LDST8 + kgrp * 8;
  const int bofs2 = (l15 + 32) * LDST8 + kgrp * 8;
  const int bofs3 = (l15 + 48) * LDST8 + kgrp * 8;

  f32x4 sr0, sr1, sr2, sr3;

  unsigned long long aj0, aj1, aj2, aj3;

  STAGE_LOAD8(0);
  aj0 = *(const unsigned long long*)(ap8 +    0);
  aj1 = *(const unsigned long long*)(ap8 +  512);
  aj2 = *(const unsigned long long*)(ap8 + 1024);
  aj3 = *(const unsigned long long*)(ap8 + 1536);
  STAGE_WRITE8(0);
  __syncthreads();

  f32x4 acc0 = {0.f, 0.f, 0.f, 0.f};
  f32x4 acc1 = {0.f, 0.f, 0.f, 0.f};
  f32x4 acc2 = {0.f, 0.f, 0.f, 0.f};
  f32x4 acc3 = {0.f, 0.f, 0.f, 0.f};

#define ITER8(II, AJ)                                                    \
  {                                                                      \
    long long a_ = (long long)AJ;                                        \
    int ci = ((t << 3) + (II) + 4) & 127;                                \
    AJ = *(const unsigned long long*)(ap8 + (size_t)ci * 512);           \
    long long b0 = *(const long long*)(bb + bofs0 + (II) * 32);          \
    long long b1 = *(const long long*)(bb + bofs1 + (II) * 32);          \
    long long b2 = *(const long long*)(bb + bofs2 + (II) * 32);          \
    long long b3 = *(const long long*)(bb + bofs3 + (II) * 32);          \
    acc0 = __builtin_amdgcn_mfma_f32_16x16x32_fp8_fp8(a_, b0, acc0, 0, 0, 0); \
    acc1 = __builtin_amdgcn_mfma_f32_16x16x32_fp8_fp8(a_, b1, acc1, 0, 0, 0); \
    acc2 = __builtin_amdgcn_mfma_f32_16x16x32_fp8_fp8(a_, b2, acc2, 0, 0, 0); \
    acc3 = __builtin_amdgcn_mfma_f32_16x16x32_fp8_fp8(a_, b3, acc3, 0, 0, 0); \
  }

  for (int t = 0; t < NCH; ++t) {
    const unsigned char* bb = Blds + (t & 1) * (64 * LDST8);
    if (t + 1 < NCH) STAGE_LOAD8((t + 1) * BK);
    ITER8(0, aj0)
    ITER8(1, aj1)
    ITER8(2, aj2)
    ITER8(3, aj3)
    ITER8(4, aj0)
    ITER8(5, aj1)
    ITER8(6, aj2)
    ITER8(7, aj3)
    if (t + 1 < NCH) STAGE_WRITE8((t + 1) & 1);
    __syncthreads();
  }

  int zr = (xb << 6) + (w << 4) + (kgrp << 2);
  float* pp = P + (size_t)yb * NV * 64 + (size_t)zr * 64 + l15;
  #pragma unroll
  for (int r = 0; r < 4; ++r) {
    pp[(size_t)r * 64 +  0] = acc0[r] * SCDN;
    pp[(size_t)r * 64 + 16] = acc1[r] * SCDN;
    pp[(size_t)r * 64 + 32] = acc2[r] * SCDN;
    pp[(size_t)r * 64 + 48] = acc3[r] * SCDN;
  }
#undef ITER8
#undef STAGE_LOAD8
#undef STAGE_WRITE8
}

// mid: x = relu((Z+ΣP)*rw1[reg]+rb1[reg]); Z = x@W2; Btq2 = fp8((x@L2)^T)
__global__ __launch_bounds__(256) void k_mid(
    float* __restrict__ Z, const float* __restrict__ P,
    const int* __restrict__ reg,
    const float* __restrict__ rw1, const float* __restrict__ rb1,
    const float* __restrict__ W2, const float* __restrict__ L2,
    unsigned char* __restrict__ Btq2) {
  __shared__ float Ws[4096], Ls[4096], xs[16 * 64];
  int tid = threadIdx.x;
  for (int i = tid; i < 4096; i += 256) { Ws[i] = W2[i]; Ls[i] = L2[i]; }
  int r = tid >> 6, c = tid & 63;
  int i0 = blockIdx.x << 4;
  #pragma unroll
  for (int m = 0; m < 4; ++m) {
    int i = i0 + r + 4 * m;
    int ri = reg[i];
    size_t o = (size_t)i * 64 + c;
    float z = Z[o] + P[o] + P[(size_t)NV * 64 + o] +
              P[(size_t)2 * NV * 64 + o] + P[(size_t)3 * NV * 64 + o];
    float x = z * rw1[ri * 64 + c] + rb1[ri * 64 + c];
    xs[(r + 4 * m) * 64 + c] = fmaxf(x, 0.f);
  }
  __syncthreads();
  float a1[4] = {0.f, 0.f, 0.f, 0.f};
  float a2[4] = {0.f, 0.f, 0.f, 0.f};
  #pragma unroll 8
  for (int k = 0; k < 64; ++k) {
    float wv = Ws[k * 64 + c];
    float lv = Ls[k * 64 + c];
    #pragma unroll
    for (int m = 0; m < 4; ++m) {
      float xv = xs[(r + 4 * m) * 64 + k];
      a1[m] += xv * wv;
      a2[m] += xv * lv;
    }
  }
  #pragma unroll
  for (int m = 0; m < 4; ++m) {
    int i = i0 + r + 4 * m;
    Z[(size_t)i * 64 + c] = a1[m];
    unsigned q = __builtin_amdgcn_cvt_pk_fp8_f32(a2[m], 0.0f, 0, false);
    Btq2[(size_t)c * BTQS + i] = (unsigned char)(q & 0xff);
  }
}

// out: x2 = relu((Z+ΣP)*rw2[reg]+rb2[reg]); out = x2 @ Wout^T + bout
__global__ __launch_bounds__(256) void k_out(
    const float* __restrict__ Z, const float* __restrict__ P,
    const int* __restrict__ reg,
    const float* __restrict__ rw2, const float* __restrict__ rb2,
    const float* __restrict__ Wout, const float* __restrict__ bout,
    float* __restrict__ out) {
  __shared__ float xs[16 * 64];
  int tid = threadIdx.x;
  int r = tid >> 6, c = tid & 63;
  int i0 = blockIdx.x << 4;
  #pragma unroll
  for (int m = 0; m < 4; ++m) {
    int i = i0 + r + 4 * m;
    int ri = reg[i];
    size_t o = (size_t)i * 64 + c;
    float z = Z[o] + P[o] + P[(size_t)NV * 64 + o] +
              P[(size_t)2 * NV * 64 + o] + P[(size_t)3 * NV * 64 + o];
    float x = z * rw2[ri * 64 + c] + rb2[ri * 64 + c];
    xs[(r + 4 * m) * 64 + c] = fmaxf(x, 0.f);
  }
  __syncthreads();
  if (c < 8) {
    #pragma unroll
    for (int m = 0; m < 4; ++m) {
      int i = i0 + r + 4 * m;
      float a = bout[c];
      #pragma unroll 8
      for (int k = 0; k < 64; ++k) a += xs[(r + 4 * m) * 64 + k] * Wout[c * 64 + k];
      out[(size_t)i * 8 + c] = a;
    }
  }
}

extern "C" void kernel_launch(void* const* d_in, const int* in_sizes, int n_in,
                              void* d_out, int out_size, void* d_ws, size_t ws_size,
                              hipStream_t stream) {
  const float* h    = (const float*)d_in[0];
  const float* adj  = (const float*)d_in[1];
  const int*   reg  = (const int*)d_in[2];
  const float* W1   = (const float*)d_in[3];
  const float* L1   = (const float*)d_in[4];
  const float* rw1  = (const float*)d_in[5];
  const float* rb1  = (const float*)d_in[6];
  const float* W2   = (const float*)d_in[7];
  const float* L2   = (const float*)d_in[8];
  const float* rw2  = (const float*)d_in[9];
  const float* rb2  = (const float*)d_in[10];
  const float* Wout = (const float*)d_in[11];
  const float* bout = (const float*)d_in[12];
  float* out = (float*)d_out;

  char* ws = (char*)d_ws;
  float* Z            = (float*)(ws);                                 // 4 MB @ 0
  unsigned char* Btq1 = (unsigned char*)(ws + ((size_t)4  << 20));    // ~1.06 MB
  float* P            = (float*)(ws + ((size_t)8  << 20));            // 16 MB (4 slices)
  unsigned char* Btq2 = (unsigned char*)(ws + ((size_t)24 << 20));    // ~1.06 MB
  unsigned char* adj8 = (unsigned char*)(ws + ((size_t)28 << 20));    // 256 MB

  k_prep<<<NV / 16, 256, 0, stream>>>(h, W1, L1, Z, Btq1);
  k_adj1<<<dim3(NV / 64, 4), 256, 0, stream>>>(adj, Btq1, P, adj8);
  k_mid<<<NV / 16, 256, 0, stream>>>(Z, P, reg, rw1, rb1, W2, L2, Btq2);
  k_adj8<<<dim3(NV / 64, 4), 256, 0, stream>>>(adj8, Btq2, P);
  k_out<<<NV / 16, 256, 0, stream>>>(Z, P, reg, rw2, rb2, Wout, bout, out);
}